// Round 5
// baseline (135.603 us; speedup 1.0000x reference)
//
#include <hip/hip_runtime.h>
#include <hip/hip_bf16.h>
#include <cstdint>
#include <cstddef>

// Problem constants (B=4, N=256, D=32, H=512)
#define NB 4
#define NN 256
#define DD 32
#define HH 512

typedef __attribute__((ext_vector_type(8))) short short8;    // 8 bf16 (4 VGPRs) — MFMA A/B frag
typedef __attribute__((ext_vector_type(4))) float f32x4;     // 16x16 C/D frag
typedef __attribute__((ext_vector_type(16))) float f32x16;   // 32x32 C/D frag

// HW packed fp32->bf16 (RNE). a -> low 16, b -> high 16.
static __device__ __forceinline__ unsigned cvtpk(float a, float b) {
  unsigned r;
  asm("v_cvt_pk_bf16_f32 %0, %1, %2" : "=v"(r) : "v"(a), "v"(b));
  return r;
}
static __device__ __forceinline__ unsigned short f2bf1(float a) {
  return (unsigned short)(cvtpk(a, 0.f) & 0xffffu);
}

// build a bf16 A/B frag from 8 consecutive fp32 (two float4 loads already done)
static __device__ __forceinline__ short8 pack8(float4 a0, float4 a1) {
  union { unsigned u[4]; short8 s; } r;
  r.u[0] = cvtpk(a0.x, a0.y); r.u[1] = cvtpk(a0.z, a0.w);
  r.u[2] = cvtpk(a1.x, a1.y); r.u[3] = cvtpk(a1.z, a1.w);
  return r.s;
}

// ---------------------------------------------------------------------------
// prep0 (grid 64x256): build W1F — W1 in bf16 B-fragment layout (see R4).
// ---------------------------------------------------------------------------
__global__ __launch_bounds__(256) void prep0(const float* __restrict__ W1,
                                             unsigned short* __restrict__ W1F) {
  const int f = blockIdx.x * 256 + threadIdx.x;   // 16384 threads, 4 rows each
  #pragma unroll
  for (int r = 0; r < 4; ++r) {
    int row = r * 16384 + f;
    int lane = row & 63;
    int nt = (row >> 6) & 7, w2 = (row >> 9) & 3, nblk = row >> 11;
    int quad = lane >> 4, l16 = lane & 15;
    int nl = w2 * 128 + l16 * 8 + nt;
    int hl = nl >> 5, c = nl & 31;
    const float* src = W1 + (size_t)(nblk * 16 + hl);
    float v[8];
    #pragma unroll
    for (int e = 0; e < 8; ++e)
      v[e] = src[(size_t)((quad * 8 + e) * 32 + c) * 512];
    uint4 p;
    p.x = cvtpk(v[0], v[1]); p.y = cvtpk(v[2], v[3]);
    p.z = cvtpk(v[4], v[5]); p.w = cvtpk(v[6], v[7]);
    *(uint4*)&W1F[(size_t)row * 8] = p;
  }
}

// ---------------------------------------------------------------------------
// prep1 (grid 641x256): T-GEMM from W1F / W2F builder / queue build / fill.
// (unchanged from R4)
// ---------------------------------------------------------------------------
__global__ __launch_bounds__(256) void prep1(const float* __restrict__ z,
                                             const unsigned short* __restrict__ W1F,
                                             const float* __restrict__ W2,
                                             const float* __restrict__ motif,
                                             unsigned short* __restrict__ W2F,
                                             unsigned short* __restrict__ Tall,
                                             int* __restrict__ jlist,
                                             int* __restrict__ jcnt,
                                             int* __restrict__ wq,
                                             int* __restrict__ wqn,
                                             float* __restrict__ out) {
  const int blk = blockIdx.x;
  const int tid = threadIdx.x;
  if (blk < 512) {
    const int nblk = blk >> 4, mgrp = blk & 15;
    const int bibase = mgrp * 64;
    const int w2 = tid >> 6, lane = tid & 63;
    const int quad = lane >> 4, l16 = lane & 15;

    short8 bfr[8];
    #pragma unroll
    for (int nt = 0; nt < 8; ++nt)
      bfr[nt] = *(const short8*)&W1F[(size_t)((((nblk * 4 + w2) * 8) + nt) * 64 + lane) * 8];

    const int ncol = nblk * 512 + w2 * 128 + l16 * 8;
    #pragma unroll
    for (int mtg = 0; mtg < 2; ++mtg) {
      short8 afr[2];
      #pragma unroll
      for (int mi = 0; mi < 2; ++mi) {
        const float* zr = z + (size_t)(bibase + (mtg * 2 + mi) * 16 + l16) * 32 + quad * 8;
        float4 a0 = *(const float4*)(zr);
        float4 a1 = *(const float4*)(zr + 4);
        afr[mi] = pack8(a0, a1);
      }
      f32x4 d[2][8];
      #pragma unroll
      for (int mi = 0; mi < 2; ++mi)
        #pragma unroll
        for (int nt = 0; nt < 8; ++nt)
          d[mi][nt] = __builtin_amdgcn_mfma_f32_16x16x32_bf16(
              afr[mi], bfr[nt], (f32x4){0.f, 0.f, 0.f, 0.f}, 0, 0, 0);
      #pragma unroll
      for (int mi = 0; mi < 2; ++mi)
        #pragma unroll
        for (int r = 0; r < 4; ++r) {
          int rowbi = bibase + (mtg * 2 + mi) * 16 + quad * 4 + r;
          if (motif[rowbi] != 0.f) {        // masked rows never read by fused
            uint4 p;
            p.x = cvtpk(d[mi][0][r], d[mi][1][r]);
            p.y = cvtpk(d[mi][2][r], d[mi][3][r]);
            p.z = cvtpk(d[mi][4][r], d[mi][5][r]);
            p.w = cvtpk(d[mi][6][r], d[mi][7][r]);
            *(uint4*)&Tall[(size_t)rowbi * 16384 + ncol] = p;
          }
        }
    }
  } else if (blk < 576) {
    int f8 = (blk - 512) * 256 + tid;       // frag-slot index (8 elems each)
    int lane = f8 & 63;
    int nt = (f8 >> 6) & 1, s = (f8 >> 7) & 3, hc = (f8 >> 9) & 7, w = (f8 >> 12) & 3;
    int k2 = w * 64 + nt * 32 + (lane & 31);
    int hb = hc * 64 + s * 16 + (lane >> 5) * 8;
    float v[8];
    #pragma unroll
    for (int e = 0; e < 8; ++e) v[e] = W2[(hb + e) * 256 + k2];
    uint4 p;
    p.x = cvtpk(v[0], v[1]); p.y = cvtpk(v[2], v[3]);
    p.z = cvtpk(v[4], v[5]); p.w = cvtpk(v[6], v[7]);
    ((uint4*)W2F)[f8] = p;
  } else if (blk == 576) {
    // ---- compaction + queue build: wave w handles batch b = w
    __shared__ int itemc[4];
    __shared__ int baseh[4];
    const int w = tid >> 6, lane = tid & 63;
    int cnt = 0;
    if (w < NB) {
      #pragma unroll
      for (int ch = 0; ch < 4; ++ch) {
        int j = ch * 64 + lane;
        float m = motif[w * 256 + j];
        bool alive = (m != 0.f);
        unsigned long long mk = __ballot(alive);
        unsigned long long below = mk & ((1ull << lane) - 1ull);
        int pos = __popcll(below);
        if (alive) jlist[w * 256 + cnt + pos] = j;
        cnt += __popcll(mk);
      }
      if (lane == 0) {
        jcnt[w] = cnt;
        itemc[w] = cnt * ((cnt + 63) >> 6);
      }
    }
    __syncthreads();
    if (tid == 0) {
      int s = 0;
      #pragma unroll
      for (int k = 0; k < NB; ++k) { baseh[k] = s; s += itemc[k]; }
      *wqn = s;
    }
    __syncthreads();
    if (w < NB) {
      const int K = (cnt + 63) >> 6;
      const int base = baseh[w];
      const int L2n = cnt * K;
      int rank = 0;
      #pragma unroll
      for (int ch = 0; ch < 4; ++ch) {
        int i = ch * 64 + lane;
        bool alive = (motif[w * 256 + i] != 0.f);
        unsigned long long mk = __ballot(alive);
        unsigned long long below = mk & ((1ull << lane) - 1ull);
        int pos = __popcll(below);
        if (alive) {
          int idx0 = (rank + pos) * K;
          for (int jt = 0; jt < K; ++jt) {
            int idx = idx0 + jt;
            int nidx = idx;
            // XCD pair-locality: place the two items of one bi 8 apart so
            // round-robin block->XCD puts them on the same XCD.
            if (K == 2) {
              int g = idx >> 4;
              if (g * 16 + 16 <= L2n)
                nidx = g * 16 + ((idx & 1) << 3) + ((idx >> 1) & 7);
            }
            wq[base + nidx] = (w * 256 + i) * 4 + jt;
          }
        }
        rank += __popcll(mk);
      }
    }
  } else {
    // ---- fill duty: constants for masked (bi,j) pairs; 64 blocks x 4096
    const size_t OUT2 = (size_t)NB * NN * NN;
    const int c = blk - 577;
    for (int p = c * 4096 + tid; p < (c + 1) * 4096; p += 256) {
      int bi = p >> 8, j = p & 255, b = bi >> 8;
      if (motif[bi] == 0.f || motif[b * 256 + j] == 0.f) {
        out[p] = 0.5f;
        out[OUT2 + p] = 0.f;
      }
    }
  }
}

// ---------------------------------------------------------------------------
// fused (round 5): register-diet variant of the champion body.
// Outer runtime loop over nt (the wave's two 32-wide k2 sub-slices):
//   acc shrinks 64 -> 32 AGPRs; phase-1 (cheap) is recomputed per nt;
//   tfr re-fetched per (nt,half) from L2; epilogue per nt into red[nt].
// All structural loops are unroll(1) to keep the allocator from hoisting
// loads across stages. launch_bounds(256,4) targets 128 regs ->
// 4 waves/SIMD -> 4 blocks/CU -> all ~1024 items co-resident in one round.
// ---------------------------------------------------------------------------
__global__ __launch_bounds__(256, 4) void fused(const unsigned short* __restrict__ Tall,
                                             const unsigned short* __restrict__ W2F,
                                             const float* __restrict__ z,
                                             const float* __restrict__ b1,
                                             const float* __restrict__ b2,
                                             const float* __restrict__ W3,
                                             const float* __restrict__ b3,
                                             const float* __restrict__ motif,
                                             const int* __restrict__ jlist,
                                             const int* __restrict__ jcnt,
                                             const int* __restrict__ wq,
                                             const int* __restrict__ wqn,
                                             float* __restrict__ out) {
  __shared__ unsigned short h1s[64 * 264];   // [slot][h_local], stride 264
  __shared__ float red[2][256];              // per-nt partial logits

  const int bx = blockIdx.x;
  const int tid = threadIdx.x;
  const size_t OUT2 = (size_t)NB * NN * NN;
  const int nq = *wqn;

  if (bx >= nq) return;                      // fill handled by prep1
  const int item = wq[bx];

  const int w = tid >> 6, lane = tid & 63;
  const int quad = lane >> 4, l16 = lane & 15;
  const int L = lane >> 5, c32 = lane & 31;

  const int bi = item >> 2, jt = item & 3;
  const int b = bi >> 8;
  const int cnt = jcnt[b];
  const int slotbase = jt * 64;
  const float mi_v = motif[bi];

  // phase-1 z frags gathered through jlist (live across the whole item)
  short8 zfr[4];
  #pragma unroll
  for (int sg = 0; sg < 4; ++sg) {
    int slot = slotbase + sg * 16 + l16;
    int sc = slot < cnt ? slot : cnt - 1;
    int jj = jlist[b * 256 + sc] & 255;
    const float* zr = z + (size_t)(b * 256 + jj) * 32 + quad * 8;
    float4 a0 = *(const float4*)(zr);
    float4 a1 = *(const float4*)(zr + 4);
    zfr[sg] = pack8(a0, a1);
  }

  const unsigned short* Tbase = Tall + (size_t)bi * 16384 + (w * 16 + l16) * 32 + quad * 8;
  const unsigned short* Wp = W2F + w * 32768 + lane * 8;
  const float* b1base = b1 + w * 16 + quad * 4;

  #pragma unroll 1
  for (int nt = 0; nt < 2; ++nt) {
    // epilogue constants for this k2 sub-slice (from L2, cheap)
    const int k2 = w * 64 + nt * 32 + c32;
    const float b2s = b2[k2];
    const float w3s = W3[k2];

    f32x16 acc[2];
    acc[0] = (f32x16){0.f,0.f,0.f,0.f,0.f,0.f,0.f,0.f,
                      0.f,0.f,0.f,0.f,0.f,0.f,0.f,0.f};
    acc[1] = acc[0];

    #pragma unroll 1
    for (int half = 0; half < 2; ++half) {
      // ---- phase 1: wave w fills h-rows {q*64 + w*16 + [0,16)} x 64 slots
      // (identical recompute for nt=1; tfr re-fetch is an L2 hit)
      short8 tfr[4];
      #pragma unroll
      for (int q = 0; q < 4; ++q)
        tfr[q] = *(const short8*)(Tbase + (half * 4 + q) * 2048);
      #pragma unroll
      for (int q = 0; q < 4; ++q) {
        float4 b1f = *(const float4*)(b1base + (half * 4 + q) * 64);
        f32x4 cin = {b1f.x, b1f.y, b1f.z, b1f.w};
        #pragma unroll
        for (int sg = 0; sg < 4; ++sg) {
          f32x4 d = __builtin_amdgcn_mfma_f32_16x16x32_bf16(
              tfr[q], zfr[sg], cin, 0, 0, 0);
          uint2 p;
          p.x = cvtpk(fmaxf(d[0], 0.f), fmaxf(d[1], 0.f));
          p.y = cvtpk(fmaxf(d[2], 0.f), fmaxf(d[3], 0.f));
          *(uint2*)&h1s[(sg * 16 + l16) * 264 + q * 64 + w * 16 + quad * 4] = p;
        }
      }
      __syncthreads();

      // ---- phase 2: 16 u-steps; B stream depth-3, A 2-deep, 2 MFMA/u
      const unsigned short* Wh = Wp + half * 16384 + nt * 512;
      const unsigned short* h1r = &h1s[c32 * 264 + L * 8];
      short8 bfp[3], afp[2][2];
      #pragma unroll
      for (int p = 0; p < 3; ++p)
        bfp[p] = *(const short8*)(Wh + p * 1024);
      afp[0][0] = *(const short8*)(h1r);
      afp[0][1] = *(const short8*)(h1r + 32 * 264);
      afp[1][0] = *(const short8*)(h1r + 16);
      afp[1][1] = *(const short8*)(h1r + 32 * 264 + 16);
      #pragma unroll
      for (int u = 0; u < 16; ++u) {
        const int cur = u & 1, bq = u % 3;
        short8 a0 = afp[cur][0], a1 = afp[cur][1];
        short8 b0 = bfp[bq];
        if (u < 14) {
          afp[cur][0] = *(const short8*)(h1r + (u + 2) * 16);
          afp[cur][1] = *(const short8*)(h1r + 32 * 264 + (u + 2) * 16);
        }
        if (u < 13)
          bfp[bq] = *(const short8*)(Wh + (u + 3) * 1024);
        acc[0] = __builtin_amdgcn_mfma_f32_32x32x16_bf16(a0, b0, acc[0], 0, 0, 0);
        acc[1] = __builtin_amdgcn_mfma_f32_32x32x16_bf16(a1, b0, acc[1], 0, 0, 0);
      }

      if (half == 1) {
        // ---- per-nt epilogue: relu(h2+b2) . W3, shfl-reduce over 32 k2 lanes
        float pr[2][16];
        #pragma unroll
        for (int mt = 0; mt < 2; ++mt)
          #pragma unroll
          for (int reg = 0; reg < 16; ++reg) {
            float v = acc[mt][reg] + b2s;
            v = v > 0.f ? v : 0.f;
            float s = v * w3s;
            s += __shfl_xor(s, 1);
            s += __shfl_xor(s, 2);
            s += __shfl_xor(s, 4);
            s += __shfl_xor(s, 8);
            s += __shfl_xor(s, 16);
            pr[mt][reg] = s;
          }
        if (c32 == 0) {
          #pragma unroll
          for (int mt = 0; mt < 2; ++mt)
            #pragma unroll
            for (int g = 0; g < 4; ++g) {
              float4 vv = {pr[mt][g * 4 + 0], pr[mt][g * 4 + 1],
                           pr[mt][g * 4 + 2], pr[mt][g * 4 + 3]};
              *(float4*)&red[nt][w * 64 + mt * 32 + g * 8 + L * 4] = vv;
            }
        }
      }
      __syncthreads();   // orders h1s reads vs next phase-1 writes;
                         // final one orders red writes vs readout
    }
  }

  if (tid < 64) {
    int slot = slotbase + tid;
    if (slot < cnt) {
      int j = jlist[b * 256 + slot] & 255;
      float logit = b3[0];
      #pragma unroll
      for (int wv = 0; wv < 4; ++wv)
        logit += red[0][wv * 64 + tid] + red[1][wv * 64 + tid];
      float mm = mi_v * motif[b * 256 + j];
      logit *= mm;
      float map = 1.f / (1.f + expf(-logit));
      size_t idx = (size_t)bi * 256 + j;
      out[idx] = map;
      out[OUT2 + idx] = logit;
    }
  }
}

// ---------------------------------------------------------------------------
extern "C" void kernel_launch(void* const* d_in, const int* in_sizes, int n_in,
                              void* d_out, int out_size, void* d_ws, size_t ws_size,
                              hipStream_t stream) {
  const float* z     = (const float*)d_in[0];
  const float* motif = (const float*)d_in[1];
  // d_in[2] residue_mask: all-ones, unused by the reference computation
  const float* W1 = (const float*)d_in[3];
  const float* b1 = (const float*)d_in[4];
  const float* W2 = (const float*)d_in[5];
  const float* b2 = (const float*)d_in[6];
  const float* W3 = (const float*)d_in[7];
  const float* b3 = (const float*)d_in[8];
  float* out = (float*)d_out;

  char* ws = (char*)d_ws;
  unsigned short* Tall = (unsigned short*)ws;                            // 32 MiB
  unsigned short* W2F  = (unsigned short*)(ws + 33554432);               // 256 KiB
  unsigned short* W1F  = (unsigned short*)(ws + 33554432 + 262144);      // 1 MiB
  char* tail = ws + 33554432 + 262144 + 1048576;
  int* jlist = (int*)(tail);                                             // 4 KiB
  int* jcnt  = (int*)(tail + 4096);                                      // 64 B
  int* wq    = (int*)(tail + 4096 + 64);                                 // 16 KiB
  int* wqn   = (int*)(tail + 4096 + 64 + 16384);                         // 64 B

  prep0<<<64, 256, 0, stream>>>(W1, W1F);
  prep1<<<641, 256, 0, stream>>>(z, W1F, W2, motif, W2F, Tall,
                                 jlist, jcnt, wq, wqn, out);
  fused<<<4096, 256, 0, stream>>>(Tall, W2F, z, b1, b2, W3, b3, motif,
                                  jlist, jcnt, wq, wqn, out);
}

// Round 7
// 130.018 us; speedup vs baseline: 1.0430x; 1.0430x over previous
//
#include <hip/hip_runtime.h>
#include <hip/hip_bf16.h>
#include <cstdint>
#include <cstddef>

// Problem constants (B=4, N=256, D=32, H=512)
#define NB 4
#define NN 256
#define DD 32
#define HH 512

typedef __attribute__((ext_vector_type(8))) short short8;    // 8 bf16 (4 VGPRs) — MFMA A/B frag
typedef __attribute__((ext_vector_type(4))) float f32x4;     // 16x16 C/D frag
typedef __attribute__((ext_vector_type(16))) float f32x16;   // 32x32 C/D frag

// HW packed fp32->bf16 (RNE). a -> low 16, b -> high 16.
static __device__ __forceinline__ unsigned cvtpk(float a, float b) {
  unsigned r;
  asm("v_cvt_pk_bf16_f32 %0, %1, %2" : "=v"(r) : "v"(a), "v"(b));
  return r;
}
static __device__ __forceinline__ unsigned short f2bf1(float a) {
  return (unsigned short)(cvtpk(a, 0.f) & 0xffffu);
}

// build a bf16 A/B frag from 8 consecutive fp32 (two float4 loads already done)
static __device__ __forceinline__ short8 pack8(float4 a0, float4 a1) {
  union { unsigned u[4]; short8 s; } r;
  r.u[0] = cvtpk(a0.x, a0.y); r.u[1] = cvtpk(a0.z, a0.w);
  r.u[2] = cvtpk(a1.x, a1.y); r.u[3] = cvtpk(a1.z, a1.w);
  return r.s;
}

// ---------------------------------------------------------------------------
// prep0 (grid 64x256): build W1F — W1 in bf16 B-fragment layout (see R4).
// ---------------------------------------------------------------------------
__global__ __launch_bounds__(256) void prep0(const float* __restrict__ W1,
                                             unsigned short* __restrict__ W1F) {
  const int f = blockIdx.x * 256 + threadIdx.x;   // 16384 threads, 4 rows each
  #pragma unroll
  for (int r = 0; r < 4; ++r) {
    int row = r * 16384 + f;
    int lane = row & 63;
    int nt = (row >> 6) & 7, w2 = (row >> 9) & 3, nblk = row >> 11;
    int quad = lane >> 4, l16 = lane & 15;
    int nl = w2 * 128 + l16 * 8 + nt;
    int hl = nl >> 5, c = nl & 31;
    const float* src = W1 + (size_t)(nblk * 16 + hl);
    float v[8];
    #pragma unroll
    for (int e = 0; e < 8; ++e)
      v[e] = src[(size_t)((quad * 8 + e) * 32 + c) * 512];
    uint4 p;
    p.x = cvtpk(v[0], v[1]); p.y = cvtpk(v[2], v[3]);
    p.z = cvtpk(v[4], v[5]); p.w = cvtpk(v[6], v[7]);
    *(uint4*)&W1F[(size_t)row * 8] = p;
  }
}

// ---------------------------------------------------------------------------
// prep1 (grid 641x256): T-GEMM from W1F / W2F builder / queue build / fill.
// (unchanged from R4 — measured ~13 us for the whole prep chain)
// ---------------------------------------------------------------------------
__global__ __launch_bounds__(256) void prep1(const float* __restrict__ z,
                                             const unsigned short* __restrict__ W1F,
                                             const float* __restrict__ W2,
                                             const float* __restrict__ motif,
                                             unsigned short* __restrict__ W2F,
                                             unsigned short* __restrict__ Tall,
                                             int* __restrict__ jlist,
                                             int* __restrict__ jcnt,
                                             int* __restrict__ wq,
                                             int* __restrict__ wqn,
                                             float* __restrict__ out) {
  const int blk = blockIdx.x;
  const int tid = threadIdx.x;
  if (blk < 512) {
    const int nblk = blk >> 4, mgrp = blk & 15;
    const int bibase = mgrp * 64;
    const int w2 = tid >> 6, lane = tid & 63;
    const int quad = lane >> 4, l16 = lane & 15;

    short8 bfr[8];
    #pragma unroll
    for (int nt = 0; nt < 8; ++nt)
      bfr[nt] = *(const short8*)&W1F[(size_t)((((nblk * 4 + w2) * 8) + nt) * 64 + lane) * 8];

    const int ncol = nblk * 512 + w2 * 128 + l16 * 8;
    #pragma unroll
    for (int mtg = 0; mtg < 2; ++mtg) {
      short8 afr[2];
      #pragma unroll
      for (int mi = 0; mi < 2; ++mi) {
        const float* zr = z + (size_t)(bibase + (mtg * 2 + mi) * 16 + l16) * 32 + quad * 8;
        float4 a0 = *(const float4*)(zr);
        float4 a1 = *(const float4*)(zr + 4);
        afr[mi] = pack8(a0, a1);
      }
      f32x4 d[2][8];
      #pragma unroll
      for (int mi = 0; mi < 2; ++mi)
        #pragma unroll
        for (int nt = 0; nt < 8; ++nt)
          d[mi][nt] = __builtin_amdgcn_mfma_f32_16x16x32_bf16(
              afr[mi], bfr[nt], (f32x4){0.f, 0.f, 0.f, 0.f}, 0, 0, 0);
      #pragma unroll
      for (int mi = 0; mi < 2; ++mi)
        #pragma unroll
        for (int r = 0; r < 4; ++r) {
          int rowbi = bibase + (mtg * 2 + mi) * 16 + quad * 4 + r;
          if (motif[rowbi] != 0.f) {        // masked rows never read by fused
            uint4 p;
            p.x = cvtpk(d[mi][0][r], d[mi][1][r]);
            p.y = cvtpk(d[mi][2][r], d[mi][3][r]);
            p.z = cvtpk(d[mi][4][r], d[mi][5][r]);
            p.w = cvtpk(d[mi][6][r], d[mi][7][r]);
            *(uint4*)&Tall[(size_t)rowbi * 16384 + ncol] = p;
          }
        }
    }
  } else if (blk < 576) {
    int f8 = (blk - 512) * 256 + tid;       // frag-slot index (8 elems each)
    int lane = f8 & 63;
    int nt = (f8 >> 6) & 1, s = (f8 >> 7) & 3, hc = (f8 >> 9) & 7, w = (f8 >> 12) & 3;
    int k2 = w * 64 + nt * 32 + (lane & 31);
    int hb = hc * 64 + s * 16 + (lane >> 5) * 8;
    float v[8];
    #pragma unroll
    for (int e = 0; e < 8; ++e) v[e] = W2[(hb + e) * 256 + k2];
    uint4 p;
    p.x = cvtpk(v[0], v[1]); p.y = cvtpk(v[2], v[3]);
    p.z = cvtpk(v[4], v[5]); p.w = cvtpk(v[6], v[7]);
    ((uint4*)W2F)[f8] = p;
  } else if (blk == 576) {
    // ---- compaction + queue build: wave w handles batch b = w
    __shared__ int itemc[4];
    __shared__ int baseh[4];
    const int w = tid >> 6, lane = tid & 63;
    int cnt = 0;
    if (w < NB) {
      #pragma unroll
      for (int ch = 0; ch < 4; ++ch) {
        int j = ch * 64 + lane;
        float m = motif[w * 256 + j];
        bool alive = (m != 0.f);
        unsigned long long mk = __ballot(alive);
        unsigned long long below = mk & ((1ull << lane) - 1ull);
        int pos = __popcll(below);
        if (alive) jlist[w * 256 + cnt + pos] = j;
        cnt += __popcll(mk);
      }
      if (lane == 0) {
        jcnt[w] = cnt;
        itemc[w] = cnt * ((cnt + 63) >> 6);
      }
    }
    __syncthreads();
    if (tid == 0) {
      int s = 0;
      #pragma unroll
      for (int k = 0; k < NB; ++k) { baseh[k] = s; s += itemc[k]; }
      *wqn = s;
    }
    __syncthreads();
    if (w < NB) {
      const int K = (cnt + 63) >> 6;
      const int base = baseh[w];
      const int L2n = cnt * K;
      int rank = 0;
      #pragma unroll
      for (int ch = 0; ch < 4; ++ch) {
        int i = ch * 64 + lane;
        bool alive = (motif[w * 256 + i] != 0.f);
        unsigned long long mk = __ballot(alive);
        unsigned long long below = mk & ((1ull << lane) - 1ull);
        int pos = __popcll(below);
        if (alive) {
          int idx0 = (rank + pos) * K;
          for (int jt = 0; jt < K; ++jt) {
            int idx = idx0 + jt;
            int nidx = idx;
            // XCD pair-locality: place the two items of one bi 8 apart so
            // round-robin block->XCD puts them on the same XCD.
            if (K == 2) {
              int g = idx >> 4;
              if (g * 16 + 16 <= L2n)
                nidx = g * 16 + ((idx & 1) << 3) + ((idx >> 1) & 7);
            }
            wq[base + nidx] = (w * 256 + i) * 4 + jt;
          }
        }
        rank += __popcll(mk);
      }
    }
  } else {
    // ---- fill duty: constants for masked (bi,j) pairs; 64 blocks x 4096
    const size_t OUT2 = (size_t)NB * NN * NN;
    const int c = blk - 577;
    for (int p = c * 4096 + tid; p < (c + 1) * 4096; p += 256) {
      int bi = p >> 8, j = p & 255, b = bi >> 8;
      if (motif[bi] == 0.f || motif[b * 256 + j] == 0.f) {
        out[p] = 0.5f;
        out[OUT2 + p] = 0.f;
      }
    }
  }
}

// ---------------------------------------------------------------------------
// fused (round 7 = round 6 resubmit; R6 bench was a container flake):
// item split across 8 waves (512 threads) so per-wave register need lands
// naturally in the <=128 tier (NO launch_bounds cap — R2/R5 proved caps
// spill):
//   wave w: col-group wcol=w&3 + sg-half sgh=w>>2 in phase 1 (8 MFMA),
//           k2-slice [32w, 32w+32) in phase 2 (1 B-load + 2 MFMA per u),
//   acc = 2 m-tiles x 16 = 32 AGPRs (was 64); tfr per-half = 16 VGPRs.
// Est. ~115 regs -> 4 waves/SIMD -> 2 blocks/CU co-resident = 16 waves/CU
// (2x the R4 champion) with each item's span split over 2x the waves.
// ---------------------------------------------------------------------------
__global__ __launch_bounds__(512) void fused(const unsigned short* __restrict__ Tall,
                                             const unsigned short* __restrict__ W2F,
                                             const float* __restrict__ z,
                                             const float* __restrict__ b1,
                                             const float* __restrict__ b2,
                                             const float* __restrict__ W3,
                                             const float* __restrict__ b3,
                                             const float* __restrict__ motif,
                                             const int* __restrict__ jlist,
                                             const int* __restrict__ jcnt,
                                             const int* __restrict__ wq,
                                             const int* __restrict__ wqn,
                                             float* __restrict__ out) {
  __shared__ unsigned short h1s[64 * 264];   // [slot][h_local], stride 264 (33.8 KB)
  __shared__ float red[512];                 // [wave][slot]   (2 KB)

  const int bx = blockIdx.x;
  const int tid = threadIdx.x;
  const size_t OUT2 = (size_t)NB * NN * NN;
  const int nq = *wqn;

  if (bx >= nq) return;                      // fill handled by prep1
  const int item = wq[bx];

  const int w = tid >> 6, lane = tid & 63;   // w in [0,8)
  const int quad = lane >> 4, l16 = lane & 15;
  const int L = lane >> 5, c32 = lane & 31;
  const int wcol = w & 3;                    // phase-1 h-col group
  const int sgh = w >> 2;                    // phase-1 slot-half (sg pair)

  const int bi = item >> 2, jt = item & 3;
  const int b = bi >> 8;
  const int cnt = jcnt[b];
  const int slotbase = jt * 64;
  const float mi_v = motif[bi];

  // phase-1 z frags: this wave's two 16-slot groups (sg = sgh*2 + {0,1})
  short8 zfr[2];
  #pragma unroll
  for (int sgl = 0; sgl < 2; ++sgl) {
    int slot = slotbase + (sgh * 2 + sgl) * 16 + l16;
    int sc = slot < cnt ? slot : cnt - 1;
    int jj = jlist[b * 256 + sc] & 255;
    const float* zr = z + (size_t)(b * 256 + jj) * 32 + quad * 8;
    float4 a0 = *(const float4*)(zr);
    float4 a1 = *(const float4*)(zr + 4);
    zfr[sgl] = pack8(a0, a1);
  }

  // epilogue constants: this wave owns k2 slice [32w, 32w+32)
  const int k2 = w * 32 + c32;
  const float b2s = b2[k2];
  const float w3s = W3[k2];

  f32x16 acc[2];
  acc[0] = (f32x16){0.f,0.f,0.f,0.f,0.f,0.f,0.f,0.f,
                    0.f,0.f,0.f,0.f,0.f,0.f,0.f,0.f};
  acc[1] = acc[0];

  const unsigned short* Tbase = Tall + (size_t)bi * 16384 + (wcol * 16 + l16) * 32 + quad * 8;
  // B base: wave w -> W2F 64-group (w>>1), 32-half (w&1)
  const unsigned short* Wp = W2F + (w >> 1) * 32768 + (w & 1) * 512 + lane * 8;
  const float* b1base = b1 + wcol * 16 + quad * 4;

  #pragma unroll 1
  for (int half = 0; half < 2; ++half) {
    // ---- phase 1: wave (wcol,sgh) fills slots [sgh*32, +32) x cols
    //      {q*64 + wcol*16 + [0,16)} of this half (8 MFMA)
    short8 tfr[4];
    #pragma unroll
    for (int q = 0; q < 4; ++q)
      tfr[q] = *(const short8*)(Tbase + (half * 4 + q) * 2048);
    #pragma unroll
    for (int q = 0; q < 4; ++q) {
      float4 b1f = *(const float4*)(b1base + (half * 4 + q) * 64);
      f32x4 cin = {b1f.x, b1f.y, b1f.z, b1f.w};
      #pragma unroll
      for (int sgl = 0; sgl < 2; ++sgl) {
        f32x4 d = __builtin_amdgcn_mfma_f32_16x16x32_bf16(
            tfr[q], zfr[sgl], cin, 0, 0, 0);
        uint2 p;
        p.x = cvtpk(fmaxf(d[0], 0.f), fmaxf(d[1], 0.f));
        p.y = cvtpk(fmaxf(d[2], 0.f), fmaxf(d[3], 0.f));
        *(uint2*)&h1s[((sgh * 2 + sgl) * 16 + l16) * 264 + q * 64 + wcol * 16 + quad * 4] = p;
      }
    }
    __syncthreads();

    // ---- phase 2: 16 u-steps; 1 B-frag (depth-3) x 2 A-frags (2 m-tiles)
    const unsigned short* Wh = Wp + half * 16384;
    const unsigned short* h1r = &h1s[c32 * 264 + L * 8];
    short8 bfp[3], afp[2][2];
    #pragma unroll
    for (int p = 0; p < 3; ++p)
      bfp[p] = *(const short8*)(Wh + p * 1024);
    afp[0][0] = *(const short8*)(h1r);
    afp[0][1] = *(const short8*)(h1r + 32 * 264);
    afp[1][0] = *(const short8*)(h1r + 16);
    afp[1][1] = *(const short8*)(h1r + 32 * 264 + 16);
    #pragma unroll
    for (int u = 0; u < 16; ++u) {
      const int cur = u & 1, bq = u % 3;
      short8 a0 = afp[cur][0], a1 = afp[cur][1];
      short8 b0 = bfp[bq];
      if (u < 14) {
        afp[cur][0] = *(const short8*)(h1r + (u + 2) * 16);
        afp[cur][1] = *(const short8*)(h1r + 32 * 264 + (u + 2) * 16);
      }
      if (u < 13)
        bfp[bq] = *(const short8*)(Wh + (u + 3) * 1024);
      acc[0] = __builtin_amdgcn_mfma_f32_32x32x16_bf16(a0, b0, acc[0], 0, 0, 0);
      acc[1] = __builtin_amdgcn_mfma_f32_32x32x16_bf16(a1, b0, acc[1], 0, 0, 0);
    }
    if (half == 0) __syncthreads();   // protect h1s before half-1 overwrites
  }

  // ---- epilogue: relu(h2+b2) . W3, reduce over this wave's 32 k2 lanes,
  //      then across 8 waves via red[wave][slot]
  float pr[2][16];
  #pragma unroll
  for (int mt = 0; mt < 2; ++mt)
    #pragma unroll
    for (int reg = 0; reg < 16; ++reg) {
      float v = acc[mt][reg] + b2s;
      v = v > 0.f ? v : 0.f;
      float s = v * w3s;
      s += __shfl_xor(s, 1);
      s += __shfl_xor(s, 2);
      s += __shfl_xor(s, 4);
      s += __shfl_xor(s, 8);
      s += __shfl_xor(s, 16);
      pr[mt][reg] = s;
    }
  if (c32 == 0) {
    // slot rows: mt*32 + g*8 + L*4 + [0,4)  (32x32 C-layout)
    #pragma unroll
    for (int mt = 0; mt < 2; ++mt)
      #pragma unroll
      for (int g = 0; g < 4; ++g) {
        float4 vv = {pr[mt][g * 4 + 0], pr[mt][g * 4 + 1],
                     pr[mt][g * 4 + 2], pr[mt][g * 4 + 3]};
        *(float4*)&red[w * 64 + mt * 32 + g * 8 + L * 4] = vv;
      }
  }
  __syncthreads();
  if (tid < 64) {
    int slot = slotbase + tid;
    if (slot < cnt) {
      int j = jlist[b * 256 + slot] & 255;
      float logit = b3[0];
      #pragma unroll
      for (int wv = 0; wv < 8; ++wv) logit += red[wv * 64 + tid];
      float mm = mi_v * motif[b * 256 + j];
      logit *= mm;
      float map = 1.f / (1.f + expf(-logit));
      size_t idx = (size_t)bi * 256 + j;
      out[idx] = map;
      out[OUT2 + idx] = logit;
    }
  }
}

// ---------------------------------------------------------------------------
extern "C" void kernel_launch(void* const* d_in, const int* in_sizes, int n_in,
                              void* d_out, int out_size, void* d_ws, size_t ws_size,
                              hipStream_t stream) {
  const float* z     = (const float*)d_in[0];
  const float* motif = (const float*)d_in[1];
  // d_in[2] residue_mask: all-ones, unused by the reference computation
  const float* W1 = (const float*)d_in[3];
  const float* b1 = (const float*)d_in[4];
  const float* W2 = (const float*)d_in[5];
  const float* b2 = (const float*)d_in[6];
  const float* W3 = (const float*)d_in[7];
  const float* b3 = (const float*)d_in[8];
  float* out = (float*)d_out;

  char* ws = (char*)d_ws;
  unsigned short* Tall = (unsigned short*)ws;                            // 32 MiB
  unsigned short* W2F  = (unsigned short*)(ws + 33554432);               // 256 KiB
  unsigned short* W1F  = (unsigned short*)(ws + 33554432 + 262144);      // 1 MiB
  char* tail = ws + 33554432 + 262144 + 1048576;
  int* jlist = (int*)(tail);                                             // 4 KiB
  int* jcnt  = (int*)(tail + 4096);                                      // 64 B
  int* wq    = (int*)(tail + 4096 + 64);                                 // 16 KiB
  int* wqn   = (int*)(tail + 4096 + 64 + 16384);                         // 64 B

  prep0<<<64, 256, 0, stream>>>(W1, W1F);
  prep1<<<641, 256, 0, stream>>>(z, W1F, W2, motif, W2F, Tall,
                                 jlist, jcnt, wq, wqn, out);
  fused<<<4096, 512, 0, stream>>>(Tall, W2F, z, b1, b2, W3, b3, motif,
                                  jlist, jcnt, wq, wqn, out);
}

// Round 8
// 123.715 us; speedup vs baseline: 1.0961x; 1.0509x over previous
//
#include <hip/hip_runtime.h>
#include <hip/hip_bf16.h>
#include <cstdint>
#include <cstddef>

// Problem constants (B=4, N=256, D=32, H=512)
#define NB 4
#define NN 256
#define DD 32
#define HH 512

typedef __attribute__((ext_vector_type(8))) short short8;    // 8 bf16 (4 VGPRs) — MFMA A/B frag
typedef __attribute__((ext_vector_type(4))) float f32x4;     // 16x16 C/D frag
typedef __attribute__((ext_vector_type(16))) float f32x16;   // 32x32 C/D frag

// HW packed fp32->bf16 (RNE). a -> low 16, b -> high 16.
static __device__ __forceinline__ unsigned cvtpk(float a, float b) {
  unsigned r;
  asm("v_cvt_pk_bf16_f32 %0, %1, %2" : "=v"(r) : "v"(a), "v"(b));
  return r;
}
static __device__ __forceinline__ unsigned short f2bf1(float a) {
  return (unsigned short)(cvtpk(a, 0.f) & 0xffffu);
}

// build a bf16 A/B frag from 8 consecutive fp32 (two float4 loads already done)
static __device__ __forceinline__ short8 pack8(float4 a0, float4 a1) {
  union { unsigned u[4]; short8 s; } r;
  r.u[0] = cvtpk(a0.x, a0.y); r.u[1] = cvtpk(a0.z, a0.w);
  r.u[2] = cvtpk(a1.x, a1.y); r.u[3] = cvtpk(a1.z, a1.w);
  return r.s;
}

// ---------------------------------------------------------------------------
// prep0 (grid 64x256): build W1F — W1 in bf16 B-fragment layout (see R4).
// ---------------------------------------------------------------------------
__global__ __launch_bounds__(256) void prep0(const float* __restrict__ W1,
                                             unsigned short* __restrict__ W1F) {
  const int f = blockIdx.x * 256 + threadIdx.x;   // 16384 threads, 4 rows each
  #pragma unroll
  for (int r = 0; r < 4; ++r) {
    int row = r * 16384 + f;
    int lane = row & 63;
    int nt = (row >> 6) & 7, w2 = (row >> 9) & 3, nblk = row >> 11;
    int quad = lane >> 4, l16 = lane & 15;
    int nl = w2 * 128 + l16 * 8 + nt;
    int hl = nl >> 5, c = nl & 31;
    const float* src = W1 + (size_t)(nblk * 16 + hl);
    float v[8];
    #pragma unroll
    for (int e = 0; e < 8; ++e)
      v[e] = src[(size_t)((quad * 8 + e) * 32 + c) * 512];
    uint4 p;
    p.x = cvtpk(v[0], v[1]); p.y = cvtpk(v[2], v[3]);
    p.z = cvtpk(v[4], v[5]); p.w = cvtpk(v[6], v[7]);
    *(uint4*)&W1F[(size_t)row * 8] = p;
  }
}

// ---------------------------------------------------------------------------
// prep1 (grid 641x256): T-GEMM from W1F / W2F builder / queue build / fill.
// (unchanged from R4 — proven)
// ---------------------------------------------------------------------------
__global__ __launch_bounds__(256) void prep1(const float* __restrict__ z,
                                             const unsigned short* __restrict__ W1F,
                                             const float* __restrict__ W2,
                                             const float* __restrict__ motif,
                                             unsigned short* __restrict__ W2F,
                                             unsigned short* __restrict__ Tall,
                                             int* __restrict__ jlist,
                                             int* __restrict__ jcnt,
                                             int* __restrict__ wq,
                                             int* __restrict__ wqn,
                                             float* __restrict__ out) {
  const int blk = blockIdx.x;
  const int tid = threadIdx.x;
  if (blk < 512) {
    const int nblk = blk >> 4, mgrp = blk & 15;
    const int bibase = mgrp * 64;
    const int w2 = tid >> 6, lane = tid & 63;
    const int quad = lane >> 4, l16 = lane & 15;

    short8 bfr[8];
    #pragma unroll
    for (int nt = 0; nt < 8; ++nt)
      bfr[nt] = *(const short8*)&W1F[(size_t)((((nblk * 4 + w2) * 8) + nt) * 64 + lane) * 8];

    const int ncol = nblk * 512 + w2 * 128 + l16 * 8;
    #pragma unroll
    for (int mtg = 0; mtg < 2; ++mtg) {
      short8 afr[2];
      #pragma unroll
      for (int mi = 0; mi < 2; ++mi) {
        const float* zr = z + (size_t)(bibase + (mtg * 2 + mi) * 16 + l16) * 32 + quad * 8;
        float4 a0 = *(const float4*)(zr);
        float4 a1 = *(const float4*)(zr + 4);
        afr[mi] = pack8(a0, a1);
      }
      f32x4 d[2][8];
      #pragma unroll
      for (int mi = 0; mi < 2; ++mi)
        #pragma unroll
        for (int nt = 0; nt < 8; ++nt)
          d[mi][nt] = __builtin_amdgcn_mfma_f32_16x16x32_bf16(
              afr[mi], bfr[nt], (f32x4){0.f, 0.f, 0.f, 0.f}, 0, 0, 0);
      #pragma unroll
      for (int mi = 0; mi < 2; ++mi)
        #pragma unroll
        for (int r = 0; r < 4; ++r) {
          int rowbi = bibase + (mtg * 2 + mi) * 16 + quad * 4 + r;
          if (motif[rowbi] != 0.f) {        // masked rows never read by fused
            uint4 p;
            p.x = cvtpk(d[mi][0][r], d[mi][1][r]);
            p.y = cvtpk(d[mi][2][r], d[mi][3][r]);
            p.z = cvtpk(d[mi][4][r], d[mi][5][r]);
            p.w = cvtpk(d[mi][6][r], d[mi][7][r]);
            *(uint4*)&Tall[(size_t)rowbi * 16384 + ncol] = p;
          }
        }
    }
  } else if (blk < 576) {
    int f8 = (blk - 512) * 256 + tid;       // frag-slot index (8 elems each)
    int lane = f8 & 63;
    int nt = (f8 >> 6) & 1, s = (f8 >> 7) & 3, hc = (f8 >> 9) & 7, w = (f8 >> 12) & 3;
    int k2 = w * 64 + nt * 32 + (lane & 31);
    int hb = hc * 64 + s * 16 + (lane >> 5) * 8;
    float v[8];
    #pragma unroll
    for (int e = 0; e < 8; ++e) v[e] = W2[(hb + e) * 256 + k2];
    uint4 p;
    p.x = cvtpk(v[0], v[1]); p.y = cvtpk(v[2], v[3]);
    p.z = cvtpk(v[4], v[5]); p.w = cvtpk(v[6], v[7]);
    ((uint4*)W2F)[f8] = p;
  } else if (blk == 576) {
    // ---- compaction + queue build: wave w handles batch b = w
    __shared__ int itemc[4];
    __shared__ int baseh[4];
    const int w = tid >> 6, lane = tid & 63;
    int cnt = 0;
    if (w < NB) {
      #pragma unroll
      for (int ch = 0; ch < 4; ++ch) {
        int j = ch * 64 + lane;
        float m = motif[w * 256 + j];
        bool alive = (m != 0.f);
        unsigned long long mk = __ballot(alive);
        unsigned long long below = mk & ((1ull << lane) - 1ull);
        int pos = __popcll(below);
        if (alive) jlist[w * 256 + cnt + pos] = j;
        cnt += __popcll(mk);
      }
      if (lane == 0) {
        jcnt[w] = cnt;
        itemc[w] = cnt * ((cnt + 63) >> 6);
      }
    }
    __syncthreads();
    if (tid == 0) {
      int s = 0;
      #pragma unroll
      for (int k = 0; k < NB; ++k) { baseh[k] = s; s += itemc[k]; }
      *wqn = s;
    }
    __syncthreads();
    if (w < NB) {
      const int K = (cnt + 63) >> 6;
      const int base = baseh[w];
      const int L2n = cnt * K;
      int rank = 0;
      #pragma unroll
      for (int ch = 0; ch < 4; ++ch) {
        int i = ch * 64 + lane;
        bool alive = (motif[w * 256 + i] != 0.f);
        unsigned long long mk = __ballot(alive);
        unsigned long long below = mk & ((1ull << lane) - 1ull);
        int pos = __popcll(below);
        if (alive) {
          int idx0 = (rank + pos) * K;
          for (int jt = 0; jt < K; ++jt) {
            int idx = idx0 + jt;
            int nidx = idx;
            // XCD pair-locality: place the two items of one bi 8 apart so
            // round-robin block->XCD puts them on the same XCD.
            if (K == 2) {
              int g = idx >> 4;
              if (g * 16 + 16 <= L2n)
                nidx = g * 16 + ((idx & 1) << 3) + ((idx >> 1) & 7);
            }
            wq[base + nidx] = (w * 256 + i) * 4 + jt;
          }
        }
        rank += __popcll(mk);
      }
    }
  } else {
    // ---- fill duty: constants for masked (bi,j) pairs; 64 blocks x 4096
    const size_t OUT2 = (size_t)NB * NN * NN;
    const int c = blk - 577;
    for (int p = c * 4096 + tid; p < (c + 1) * 4096; p += 256) {
      int bi = p >> 8, j = p & 255, b = bi >> 8;
      if (motif[bi] == 0.f || motif[b * 256 + j] == 0.f) {
        out[p] = 0.5f;
        out[OUT2 + p] = 0.f;
      }
    }
  }
}

// ---------------------------------------------------------------------------
// fused (round 8): R4 champion body restructured to break the 2-phase convoy
// (the known ~18% MfmaUtil structural ceiling, cf. m233):
//   - h1s double-buffered (2 x 33.8 KB) -> P1(half1) runs CONCURRENT with
//     P2(half0) in one barrier region (one convoy point removed; MFMA16s and
//     ds_writes of P1(1) fill P2(0)'s load-wait bubbles)
//   - B-stream (W2F) 8-deep pipelined across the WHOLE item: init hoisted to
//     item start; during P2(0)'s u>=8 steps the dead slots prefetch half-1's
//     rows -> no exposed B-init latency anywhere
//   - tfr per-half (4 frags, half-1 reload is an L2 hit) to hold VGPRs
// No launch_bounds cap (R2/R5: caps spill). Est ~220 regs -> 2 waves/SIMD,
// 2 blocks/CU (= LDS cap) — R7 proved occupancy is not the lever, overlap is.
// ---------------------------------------------------------------------------
__global__ __launch_bounds__(256) void fused(const unsigned short* __restrict__ Tall,
                                             const unsigned short* __restrict__ W2F,
                                             const float* __restrict__ z,
                                             const float* __restrict__ b1,
                                             const float* __restrict__ b2,
                                             const float* __restrict__ W3,
                                             const float* __restrict__ b3,
                                             const float* __restrict__ motif,
                                             const int* __restrict__ jlist,
                                             const int* __restrict__ jcnt,
                                             const int* __restrict__ wq,
                                             const int* __restrict__ wqn,
                                             float* __restrict__ out) {
  __shared__ unsigned short h1s[2][64 * 264];  // double-buffered [half][slot][h]
  __shared__ float red[256];

  const int bx = blockIdx.x;
  const int tid = threadIdx.x;
  const size_t OUT2 = (size_t)NB * NN * NN;
  const int nq = *wqn;

  if (bx >= nq) return;                      // fill handled by prep1
  const int item = wq[bx];

  const int w = tid >> 6, lane = tid & 63;
  const int quad = lane >> 4, l16 = lane & 15;
  const int L = lane >> 5, c32 = lane & 31;

  const int bi = item >> 2, jt = item & 3;
  const int b = bi >> 8;
  const int cnt = jcnt[b];
  const int slotbase = jt * 64;
  const float mi_v = motif[bi];

  const unsigned short* Tbase = Tall + (size_t)bi * 16384 + (w * 16 + l16) * 32 + quad * 8;
  const unsigned short* Wp = W2F + w * 32768 + lane * 8;
  const float* b1base = b1 + w * 16 + quad * 4;

  // ---- hoisted B init: half-0 rows 0..7, in flight under zfr/tfr/P1(0)
  short8 bfp[8][2];
  #pragma unroll
  for (int p = 0; p < 8; ++p) {
    bfp[p][0] = *(const short8*)(Wp + p * 1024);
    bfp[p][1] = *(const short8*)(Wp + p * 1024 + 512);
  }

  // phase-1 z frags gathered through jlist
  short8 zfr[4];
  #pragma unroll
  for (int sg = 0; sg < 4; ++sg) {
    int slot = slotbase + sg * 16 + l16;
    int sc = slot < cnt ? slot : cnt - 1;
    int jj = jlist[b * 256 + sc] & 255;
    const float* zr = z + (size_t)(b * 256 + jj) * 32 + quad * 8;
    float4 a0 = *(const float4*)(zr);
    float4 a1 = *(const float4*)(zr + 4);
    zfr[sg] = pack8(a0, a1);
  }

  // epilogue constants: this wave owns k2 in [64w, 64w+64)
  float b2v[2], w3v[2];
  #pragma unroll
  for (int nt = 0; nt < 2; ++nt) {
    int k2 = w * 64 + nt * 32 + c32;
    b2v[nt] = b2[k2];
    w3v[nt] = W3[k2];
  }

  f32x16 acc[2][2];
  #pragma unroll
  for (int mt = 0; mt < 2; ++mt)
    #pragma unroll
    for (int nt = 0; nt < 2; ++nt)
      acc[mt][nt] = (f32x16){0.f,0.f,0.f,0.f,0.f,0.f,0.f,0.f,
                             0.f,0.f,0.f,0.f,0.f,0.f,0.f,0.f};

  short8 tfr[4];

  // ---- phase 1, half 0 -> h1s[0]
  #pragma unroll
  for (int q = 0; q < 4; ++q)
    tfr[q] = *(const short8*)(Tbase + q * 2048);
  #pragma unroll
  for (int q = 0; q < 4; ++q) {
    float4 b1f = *(const float4*)(b1base + q * 64);
    f32x4 cin = {b1f.x, b1f.y, b1f.z, b1f.w};
    #pragma unroll
    for (int sg = 0; sg < 4; ++sg) {
      f32x4 d = __builtin_amdgcn_mfma_f32_16x16x32_bf16(tfr[q], zfr[sg], cin, 0, 0, 0);
      uint2 p;
      p.x = cvtpk(fmaxf(d[0], 0.f), fmaxf(d[1], 0.f));
      p.y = cvtpk(fmaxf(d[2], 0.f), fmaxf(d[3], 0.f));
      *(uint2*)&h1s[0][(sg * 16 + l16) * 264 + q * 64 + w * 16 + quad * 4] = p;
    }
  }
  __syncthreads();

  // ---- merged region: P1(half 1) -> h1s[1]  ||  P2(half 0) from h1s[0]
  #pragma unroll
  for (int q = 0; q < 4; ++q)
    tfr[q] = *(const short8*)(Tbase + (4 + q) * 2048);   // L2 hit (line hot)
  #pragma unroll
  for (int q = 0; q < 4; ++q) {
    float4 b1f = *(const float4*)(b1base + (4 + q) * 64);
    f32x4 cin = {b1f.x, b1f.y, b1f.z, b1f.w};
    #pragma unroll
    for (int sg = 0; sg < 4; ++sg) {
      f32x4 d = __builtin_amdgcn_mfma_f32_16x16x32_bf16(tfr[q], zfr[sg], cin, 0, 0, 0);
      uint2 p;
      p.x = cvtpk(fmaxf(d[0], 0.f), fmaxf(d[1], 0.f));
      p.y = cvtpk(fmaxf(d[2], 0.f), fmaxf(d[3], 0.f));
      *(uint2*)&h1s[1][(sg * 16 + l16) * 264 + q * 64 + w * 16 + quad * 4] = p;
    }
  }
  {
    // P2(half 0): 16 u-steps; bfp preloaded (rows 0..7), prefetch rows 8..15
    // at u<8, then half-1 rows 0..7 at u>=8 (dead slots).
    const unsigned short* Wh = Wp;
    const unsigned short* Wh1 = Wp + 16384;
    const unsigned short* h1r = &h1s[0][c32 * 264 + L * 8];
    short8 afp[2][2];
    afp[0][0] = *(const short8*)(h1r);
    afp[0][1] = *(const short8*)(h1r + 32 * 264);
    afp[1][0] = *(const short8*)(h1r + 16);
    afp[1][1] = *(const short8*)(h1r + 32 * 264 + 16);
    #pragma unroll
    for (int u = 0; u < 16; ++u) {
      const int cur = u & 1, bq = u & 7;
      short8 a0 = afp[cur][0], a1 = afp[cur][1];
      short8 b0 = bfp[bq][0], b1q = bfp[bq][1];
      if (u < 14) {
        afp[cur][0] = *(const short8*)(h1r + (u + 2) * 16);
        afp[cur][1] = *(const short8*)(h1r + 32 * 264 + (u + 2) * 16);
      }
      if (u < 8) {
        bfp[bq][0] = *(const short8*)(Wh + (u + 8) * 1024);
        bfp[bq][1] = *(const short8*)(Wh + (u + 8) * 1024 + 512);
      } else {
        bfp[bq][0] = *(const short8*)(Wh1 + (u - 8) * 1024);
        bfp[bq][1] = *(const short8*)(Wh1 + (u - 8) * 1024 + 512);
      }
      acc[0][0] = __builtin_amdgcn_mfma_f32_32x32x16_bf16(a0, b0, acc[0][0], 0, 0, 0);
      acc[0][1] = __builtin_amdgcn_mfma_f32_32x32x16_bf16(a0, b1q, acc[0][1], 0, 0, 0);
      acc[1][0] = __builtin_amdgcn_mfma_f32_32x32x16_bf16(a1, b0, acc[1][0], 0, 0, 0);
      acc[1][1] = __builtin_amdgcn_mfma_f32_32x32x16_bf16(a1, b1q, acc[1][1], 0, 0, 0);
    }
  }
  __syncthreads();

  // ---- P2(half 1) from h1s[1]; bfp holds half-1 rows 0..7 already
  {
    const unsigned short* Wh = Wp + 16384;
    const unsigned short* h1r = &h1s[1][c32 * 264 + L * 8];
    short8 afp[2][2];
    afp[0][0] = *(const short8*)(h1r);
    afp[0][1] = *(const short8*)(h1r + 32 * 264);
    afp[1][0] = *(const short8*)(h1r + 16);
    afp[1][1] = *(const short8*)(h1r + 32 * 264 + 16);
    #pragma unroll
    for (int u = 0; u < 16; ++u) {
      const int cur = u & 1, bq = u & 7;
      short8 a0 = afp[cur][0], a1 = afp[cur][1];
      short8 b0 = bfp[bq][0], b1q = bfp[bq][1];
      if (u < 14) {
        afp[cur][0] = *(const short8*)(h1r + (u + 2) * 16);
        afp[cur][1] = *(const short8*)(h1r + 32 * 264 + (u + 2) * 16);
      }
      if (u < 8) {
        bfp[bq][0] = *(const short8*)(Wh + (u + 8) * 1024);
        bfp[bq][1] = *(const short8*)(Wh + (u + 8) * 1024 + 512);
      }
      acc[0][0] = __builtin_amdgcn_mfma_f32_32x32x16_bf16(a0, b0, acc[0][0], 0, 0, 0);
      acc[0][1] = __builtin_amdgcn_mfma_f32_32x32x16_bf16(a0, b1q, acc[0][1], 0, 0, 0);
      acc[1][0] = __builtin_amdgcn_mfma_f32_32x32x16_bf16(a1, b0, acc[1][0], 0, 0, 0);
      acc[1][1] = __builtin_amdgcn_mfma_f32_32x32x16_bf16(a1, b1q, acc[1][1], 0, 0, 0);
    }
  }

  // ---- epilogue: relu(h2+b2) . W3, reduce over k2 (32 lanes), then 4 waves
  float pr[2][16];
  #pragma unroll
  for (int mt = 0; mt < 2; ++mt)
    #pragma unroll
    for (int reg = 0; reg < 16; ++reg) {
      float s = 0.f;
      #pragma unroll
      for (int nt = 0; nt < 2; ++nt) {
        float v = acc[mt][nt][reg] + b2v[nt];
        v = v > 0.f ? v : 0.f;
        s += v * w3v[nt];
      }
      s += __shfl_xor(s, 1);
      s += __shfl_xor(s, 2);
      s += __shfl_xor(s, 4);
      s += __shfl_xor(s, 8);
      s += __shfl_xor(s, 16);
      pr[mt][reg] = s;
    }
  if (c32 == 0) {
    #pragma unroll
    for (int mt = 0; mt < 2; ++mt)
      #pragma unroll
      for (int g = 0; g < 4; ++g) {
        float4 vv = {pr[mt][g * 4 + 0], pr[mt][g * 4 + 1],
                     pr[mt][g * 4 + 2], pr[mt][g * 4 + 3]};
        *(float4*)&red[w * 64 + mt * 32 + g * 8 + L * 4] = vv;
      }
  }
  __syncthreads();
  if (tid < 64) {
    int slot = slotbase + tid;
    if (slot < cnt) {
      int j = jlist[b * 256 + slot] & 255;
      float logit = red[tid] + red[64 + tid] + red[128 + tid] + red[192 + tid] + b3[0];
      float mm = mi_v * motif[b * 256 + j];
      logit *= mm;
      float map = 1.f / (1.f + expf(-logit));
      size_t idx = (size_t)bi * 256 + j;
      out[idx] = map;
      out[OUT2 + idx] = logit;
    }
  }
}

// ---------------------------------------------------------------------------
extern "C" void kernel_launch(void* const* d_in, const int* in_sizes, int n_in,
                              void* d_out, int out_size, void* d_ws, size_t ws_size,
                              hipStream_t stream) {
  const float* z     = (const float*)d_in[0];
  const float* motif = (const float*)d_in[1];
  // d_in[2] residue_mask: all-ones, unused by the reference computation
  const float* W1 = (const float*)d_in[3];
  const float* b1 = (const float*)d_in[4];
  const float* W2 = (const float*)d_in[5];
  const float* b2 = (const float*)d_in[6];
  const float* W3 = (const float*)d_in[7];
  const float* b3 = (const float*)d_in[8];
  float* out = (float*)d_out;

  char* ws = (char*)d_ws;
  unsigned short* Tall = (unsigned short*)ws;                            // 32 MiB
  unsigned short* W2F  = (unsigned short*)(ws + 33554432);               // 256 KiB
  unsigned short* W1F  = (unsigned short*)(ws + 33554432 + 262144);      // 1 MiB
  char* tail = ws + 33554432 + 262144 + 1048576;
  int* jlist = (int*)(tail);                                             // 4 KiB
  int* jcnt  = (int*)(tail + 4096);                                      // 64 B
  int* wq    = (int*)(tail + 4096 + 64);                                 // 16 KiB
  int* wqn   = (int*)(tail + 4096 + 64 + 16384);                         // 64 B

  prep0<<<64, 256, 0, stream>>>(W1, W1F);
  prep1<<<641, 256, 0, stream>>>(z, W1F, W2, motif, W2F, Tall,
                                 jlist, jcnt, wq, wqn, out);
  fused<<<4096, 256, 0, stream>>>(Tall, W2F, z, b1, b2, W3, b3, motif,
                                  jlist, jcnt, wq, wqn, out);
}